// Round 31
// baseline (77.627 us; speedup 1.0000x reference)
//
#include <hip/hip_runtime.h>
#include <hip/hip_bf16.h>

#define NB 16
#define CIN 256
#define CA 32
#define CH 128
#define NN 4096
#define MM 1024

typedef __attribute__((ext_vector_type(8))) short s16x8;
typedef __attribute__((ext_vector_type(4))) float f32x4;

static __device__ __forceinline__ unsigned short f2bf(float x) {
  __hip_bfloat16 h = __float2bfloat16(x);
  return __builtin_bit_cast(unsigned short, h);
}
static __device__ __forceinline__ float bf2f(unsigned short u) {
  unsigned int v = ((unsigned int)u) << 16;
  return __builtin_bit_cast(float, v);
}
static __device__ __forceinline__ unsigned int pk2(float a, float b) {
  return (unsigned)f2bf(a) | ((unsigned)f2bf(b) << 16);
}
// truncating bf16 pack (no RNE): safe for P/O (error normalizes out via denom).
static __device__ __forceinline__ unsigned int pk2t(float a, float b) {
  return (__builtin_bit_cast(unsigned int, a) >> 16) |
         (__builtin_bit_cast(unsigned int, b) & 0xffff0000u);
}
// async global->LDS DMA, 16B per lane; lds dst is wave-uniform base + lane*16
static __device__ __forceinline__ void gload_lds16(const void* g, void* s) {
  __builtin_amdgcn_global_load_lds(
      (const __attribute__((address_space(1))) unsigned int*)g,
      (__attribute__((address_space(3))) unsigned int*)s, 16, 0, 0);
}

// Build wcat2 (A-fragment-packed [w_theta; w_phi; w_g]) and wo2 (fragment-packed).
__global__ __launch_bounds__(256) void k_wcvt(const float* __restrict__ w_theta,
                                              const float* __restrict__ w_phi,
                                              const float* __restrict__ w_g,
                                              const float* __restrict__ w_o,
                                              unsigned short* __restrict__ wcat2,
                                              unsigned short* __restrict__ wo2) {
  const int i = blockIdx.x * 256 + threadIdx.x;
  if (i < 49152) {
    const int row = i >> 8, c = i & 255;
    const float v = (row < 32) ? w_theta[i]
                  : (row < 64) ? w_phi[i - 8192]
                               : w_g[i - 16384];
    const int dst = ((row >> 4) * 8 + (c >> 5)) * 512 +
                    (((c >> 3) & 3) * 16 + (row & 15)) * 8 + (c & 7);
    wcat2[dst] = f2bf(v);
  } else {
    const int w = i - 49152;
    const int c_out = w >> 7, k = w & 127;
    const int dst = (((c_out >> 4) * 16) + ((k >> 5) * 4) + ((k >> 3) & 3)) * 128 +
                    ((c_out & 15) << 3) + (k & 7);
    wo2[dst] = f2bf(w_o[w]);
  }
}

// MFMA projection v4 (r23): r18 structure + T14 async-STAGE split.
// g2 V-fragments use the pi-permuted k-slot order so attn's P stays in registers.
__global__ __launch_bounds__(512) void k_proj(const float* __restrict__ x,
                                              const unsigned short* __restrict__ wcat2,
                                              unsigned short* __restrict__ theta,
                                              unsigned short* __restrict__ phi2,
                                              unsigned short* __restrict__ g2) {
  __shared__ unsigned short lds[192 * 136];  // union: xl2[2][32][132] | ol[192][136]
  unsigned short (*xl)[32][132] = reinterpret_cast<unsigned short(*)[32][132]>(lds);
  unsigned short (*ol)[136] = reinterpret_cast<unsigned short(*)[136]>(lds);
  const int b = blockIdx.y;
  const int t = blockIdx.x;
  const int tid = threadIdx.x;
  const int wv = tid >> 6;
  const int l = tid & 63;
  const int grp = l >> 4, col = l & 15;
  const float* xb = x + (size_t)b * CIN * NN;
  const int cl0 = tid >> 5, nq0 = tid & 31;
  const int cl1 = (tid + 512) >> 5, nq1 = tid & 31;
  float4 ra0, ra1;  // in-flight loads for the next chunk
  auto LOADX = [&](int kc) {
    ra0 = *reinterpret_cast<const float4*>(xb + (size_t)(kc * 32 + cl0) * NN + t * 128 + nq0 * 4);
    ra1 = *reinterpret_cast<const float4*>(xb + (size_t)(kc * 32 + cl1) * NN + t * 128 + nq1 * 4);
  };
  auto WRITEX = [&](int buf) {
    *reinterpret_cast<uint2*>(&xl[buf][cl0][nq0 * 4]) =
        make_uint2(pk2(ra0.x, ra0.y), pk2(ra0.z, ra0.w));
    *reinterpret_cast<uint2*>(&xl[buf][cl1][nq1 * 4]) =
        make_uint2(pk2(ra1.x, ra1.y), pk2(ra1.z, ra1.w));
  };
  f32x4 acc[12];
#pragma unroll
  for (int r = 0; r < 12; ++r) acc[r] = f32x4{0.f, 0.f, 0.f, 0.f};
  LOADX(0);
  WRITEX(0);
  LOADX(1);
#pragma unroll 1
  for (int kc = 0; kc < 8; ++kc) {
    __syncthreads();
    if (kc < 7) {
      WRITEX((kc + 1) & 1);
      if (kc < 6) LOADX(kc + 2);
    }
    const int cur = kc & 1;
    s16x8 bfrag;
#pragma unroll
    for (int j = 0; j < 8; ++j)
      bfrag[j] = (short)xl[cur][grp * 8 + j][wv * 16 + col];
#pragma unroll
    for (int r = 0; r < 12; ++r) {
      const s16x8 af = *reinterpret_cast<const s16x8*>(
          wcat2 + (size_t)(r * 8 + kc) * 512 + l * 8);
      acc[r] = __builtin_amdgcn_mfma_f32_16x16x32_bf16(af, bfrag, acc[r], 0, 0, 0);
    }
  }
  __syncthreads();
#pragma unroll
  for (int r = 0; r < 12; ++r)
#pragma unroll
    for (int q = 0; q < 4; ++q)
      ol[r * 16 + grp * 4 + q][wv * 16 + col] = f2bf(acc[r][q]);
  __syncthreads();
  unsigned short* thb = theta + (size_t)b * NN * CA;
  for (int i = tid; i < 128 * 16; i += 512) {
    const int n = i >> 4, cp = (i & 15) << 1;
    const unsigned int v = (unsigned)ol[cp][n] | ((unsigned)ol[cp + 1][n] << 16);
    *reinterpret_cast<unsigned int*>(thb + (size_t)(t * 128 + n) * CA + cp) = v;
  }
  unsigned short* phb2 = phi2 + (size_t)b * MM * CA;
  for (int i = tid; i < 32 * 32; i += 512) {
    const int ca = i & 31, mx = i >> 5;
    const float v = fmaxf(
        fmaxf(bf2f(ol[32 + ca][2 * mx]), bf2f(ol[32 + ca][2 * mx + 1])),
        fmaxf(bf2f(ol[32 + ca][64 + 2 * mx]), bf2f(ol[32 + ca][64 + 2 * mx + 1])));
    const int m = t * 32 + mx;
    phb2[(m >> 4) * 512 + (ca >> 3) * 128 + (m & 15) * 8 + (ca & 7)] = f2bf(v);
  }
  unsigned short* gb2 = g2 + (size_t)b * CH * MM;
  for (int i = tid; i < 128 * 32; i += 512) {
    const int mx = i & 31, c = i >> 5;
    const float v = fmaxf(
        fmaxf(bf2f(ol[64 + c][2 * mx]), bf2f(ol[64 + c][2 * mx + 1])),
        fmaxf(bf2f(ol[64 + c][64 + 2 * mx]), bf2f(ol[64 + c][64 + 2 * mx + 1])));
    const int pg = (mx & 15) >> 2;                       // pi: lane group
    const int pj = (mx & 3) | ((mx >> 4) << 2);          // pi: k-slot
    gb2[(size_t)(t * 8 + (c >> 4)) * 512 + pg * 128 + (c & 15) * 8 + pj] = f2bf(v);
  }
}

// Flash attention v16: 4-WAVE BLOCKS (64 cols), 64-key dbuf tiles, 4 blocks/CU.
// Quarter-width barriers decouple independent blocks on a CU. Register-P (pi),
// first-tile max, deferred denominator, truncating pack.
__global__ __launch_bounds__(256, 4) void k_attn_out(
    const unsigned short* __restrict__ theta, const unsigned short* __restrict__ phi2,
    const unsigned short* __restrict__ g2, const unsigned short* __restrict__ wo2,
    const float* __restrict__ x, const float* __restrict__ gammap,
    float* __restrict__ out) {
  __shared__ __align__(16) unsigned short kv[2][10240];  // [buf][K 2048 | V 8192]
  const int b = blockIdx.y;
  const int tid = threadIdx.x;
  const int wv = tid >> 6;  // 0..3
  const int l = tid & 63;
  const int grp = l >> 4, col = l & 15;
  const int n0 = blockIdx.x * 64 + wv * 16;
  const unsigned short* thb = theta + (size_t)b * NN * CA;
  const unsigned short* ph2b = phi2 + (size_t)b * MM * CA;
  const unsigned short* gb2 = g2 + (size_t)b * CH * MM;
  const s16x8 qf = *reinterpret_cast<const s16x8*>(thb + (size_t)(n0 + col) * CA + grp * 8);

  // 20 x 1KB DMA split over 4 waves (5 each)
  auto STAGE = [&](int buf, int tile) {
    const int mc = tile * 64;
    const unsigned short* ksrc = ph2b + (mc >> 4) * 512;
    const unsigned short* vsrc = gb2 + (size_t)(mc >> 5) * 4096;
#pragma unroll
    for (int q = 0; q < 5; ++q) {
      const int i = wv + q * 4;
      const unsigned short* src = (i < 4) ? (ksrc + i * 512) : (vsrc + (size_t)(i - 4) * 512);
      gload_lds16(src + (size_t)l * 8, &kv[buf][i * 512]);
    }
  };

  f32x4 oa[8];
#pragma unroll
  for (int t = 0; t < 8; ++t) oa[t] = f32x4{0.f, 0.f, 0.f, 0.f};
  float m0 = 0.f, ls = 0.f;  // m0 anchored at tile 0; ls: per-lane partial denom
  const f32x4 z4 = {0.f, 0.f, 0.f, 0.f};

  STAGE(0, 0);
  __syncthreads();
#pragma unroll 1
  for (int it = 0; it < 16; ++it) {
    const int cur = it & 1;
    if (it < 15) STAGE(cur ^ 1, it + 1);  // fire-and-forget DMA for next tile
    const unsigned short* kb = &kv[cur][0];
    const unsigned short* vb = &kv[cur][2048];
    const int fo = grp * 128 + col * 8;
    const s16x8 kf0 = *reinterpret_cast<const s16x8*>(kb + 0 * 512 + fo);
    const s16x8 kf1 = *reinterpret_cast<const s16x8*>(kb + 1 * 512 + fo);
    const s16x8 kf2 = *reinterpret_cast<const s16x8*>(kb + 2 * 512 + fo);
    const s16x8 kf3 = *reinterpret_cast<const s16x8*>(kb + 3 * 512 + fo);
    f32x4 s0 = __builtin_amdgcn_mfma_f32_16x16x32_bf16(kf0, qf, z4, 0, 0, 0);
    f32x4 s1 = __builtin_amdgcn_mfma_f32_16x16x32_bf16(kf1, qf, z4, 0, 0, 0);
    f32x4 s2 = __builtin_amdgcn_mfma_f32_16x16x32_bf16(kf2, qf, z4, 0, 0, 0);
    f32x4 s3 = __builtin_amdgcn_mfma_f32_16x16x32_bf16(kf3, qf, z4, 0, 0, 0);
    if (it == 0) {  // one exact cross-lane max; anchor for the whole row
      float cm = -INFINITY;
#pragma unroll
      for (int r = 0; r < 4; ++r)
        cm = fmaxf(cm, fmaxf(fmaxf(s0[r], s1[r]), fmaxf(s2[r], s3[r])));
      cm = fmaxf(cm, __shfl_xor(cm, 16));
      cm = fmaxf(cm, __shfl_xor(cm, 32));
      m0 = cm;
    }
    float p0[4], p1[4], p2[4], p3[4];
    float cs = 0.f;
#pragma unroll
    for (int r = 0; r < 4; ++r) {
      p0[r] = __expf(s0[r] - m0);
      p1[r] = __expf(s1[r] - m0);
      p2[r] = __expf(s2[r] - m0);
      p3[r] = __expf(s3[r] - m0);
      cs += (p0[r] + p1[r]) + (p2[r] + p3[r]);
    }
    ls += cs;  // deferred: no cross-lane reduce in the loop
    const uint4 ua = make_uint4(pk2t(p0[0], p0[1]), pk2t(p0[2], p0[3]),
                                pk2t(p1[0], p1[1]), pk2t(p1[2], p1[3]));
    const uint4 ub = make_uint4(pk2t(p2[0], p2[1]), pk2t(p2[2], p2[3]),
                                pk2t(p3[0], p3[1]), pk2t(p3[2], p3[3]));
    const s16x8 pfA = __builtin_bit_cast(s16x8, ua);
    const s16x8 pfB = __builtin_bit_cast(s16x8, ub);
#pragma unroll
    for (int t = 0; t < 8; ++t) {
      const s16x8 vfA = *reinterpret_cast<const s16x8*>(vb + t * 512 + fo);
      const s16x8 vfB = *reinterpret_cast<const s16x8*>(vb + 4096 + t * 512 + fo);
      oa[t] = __builtin_amdgcn_mfma_f32_16x16x32_bf16(vfA, pfA, oa[t], 0, 0, 0);
      oa[t] = __builtin_amdgcn_mfma_f32_16x16x32_bf16(vfB, pfB, oa[t], 0, 0, 0);
    }
    __syncthreads();  // drains DMA (vmcnt) + syncs buffer swap (4 waves only)
  }
  // final denominator reduce (deferred from loop)
  ls += __shfl_xor(ls, 16);
  ls += __shfl_xor(ls, 32);
  // ---- epilogue: normalize own O, stage in LDS (reuse kv), project ----
  unsigned short* obw = &kv[0][0] + (size_t)wv * (16 * 136);
  const float ri = 1.f / ls;
#pragma unroll
  for (int t = 0; t < 8; ++t) {
    *reinterpret_cast<uint2*>(obw + col * 136 + t * 16 + grp * 4) =
        make_uint2(pk2t(oa[t][0] * ri, oa[t][1] * ri),
                   pk2t(oa[t][2] * ri, oa[t][3] * ri));
  }
  s16x8 of[4];
#pragma unroll
  for (int ks = 0; ks < 4; ++ks)
    of[ks] = *reinterpret_cast<const s16x8*>(obw + col * 136 + ks * 32 + grp * 8);
  const float gamma = gammap[0];
  const float* xb2 = x + (size_t)b * CIN * NN;
  float* outb = out + (size_t)b * CIN * NN;
#pragma unroll 1
  for (int t2 = 0; t2 < 16; ++t2) {
    f32x4 a2 = {0.f, 0.f, 0.f, 0.f};
#pragma unroll
    for (int ks = 0; ks < 4; ++ks) {
      const s16x8 wf = *reinterpret_cast<const s16x8*>(
          wo2 + (size_t)(t2 * 16 + ks * 4 + grp) * 128 + col * 8);
      a2 = __builtin_amdgcn_mfma_f32_16x16x32_bf16(wf, of[ks], a2, 0, 0, 0);
    }
#pragma unroll
    for (int r = 0; r < 4; ++r) {
      const size_t idx = (size_t)(t2 * 16 + grp * 4 + r) * NN + n0 + col;
      outb[idx] = fmaf(gamma, a2[r], xb2[idx]);
    }
  }
}

extern "C" void kernel_launch(void* const* d_in, const int* in_sizes, int n_in,
                              void* d_out, int out_size, void* d_ws, size_t ws_size,
                              hipStream_t stream) {
  const float* x = (const float*)d_in[0];
  const float* w_theta = (const float*)d_in[1];
  const float* w_phi = (const float*)d_in[2];
  const float* w_g = (const float*)d_in[3];
  const float* w_o = (const float*)d_in[4];
  const float* gamma = (const float*)d_in[5];
  float* out = (float*)d_out;
  char* ws = (char*)d_ws;
  unsigned short* theta = (unsigned short*)(ws + 0);
  unsigned short* phi2 = (unsigned short*)(ws + 4194304);
  unsigned short* g2 = (unsigned short*)(ws + 5242880);
  unsigned short* wo2 = (unsigned short*)(ws + 9437184);
  unsigned short* wcat2 = (unsigned short*)(ws + 9502720);

  k_wcvt<<<dim3(320), 256, 0, stream>>>(w_theta, w_phi, w_g, w_o, wcat2, wo2);
  k_proj<<<dim3(NN / 128, NB), 512, 0, stream>>>(x, wcat2, theta, phi2, g2);
  k_attn_out<<<dim3(NN / 64, NB), 256, 0, stream>>>(theta, phi2, g2, wo2, x, gamma, out);
}

// Round 32
// 73.604 us; speedup vs baseline: 1.0547x; 1.0547x over previous
//
#include <hip/hip_runtime.h>
#include <hip/hip_bf16.h>

#define NB 16
#define CIN 256
#define CA 32
#define CH 128
#define NN 4096
#define MM 1024

typedef __attribute__((ext_vector_type(8))) short s16x8;
typedef __attribute__((ext_vector_type(4))) float f32x4;

static __device__ __forceinline__ unsigned short f2bf(float x) {
  __hip_bfloat16 h = __float2bfloat16(x);
  return __builtin_bit_cast(unsigned short, h);
}
static __device__ __forceinline__ float bf2f(unsigned short u) {
  unsigned int v = ((unsigned int)u) << 16;
  return __builtin_bit_cast(float, v);
}
static __device__ __forceinline__ unsigned int pk2(float a, float b) {
  return (unsigned)f2bf(a) | ((unsigned)f2bf(b) << 16);
}
// truncating bf16 pack (no RNE): safe for P/O (error normalizes out via denom).
static __device__ __forceinline__ unsigned int pk2t(float a, float b) {
  return (__builtin_bit_cast(unsigned int, a) >> 16) |
         (__builtin_bit_cast(unsigned int, b) & 0xffff0000u);
}
// async global->LDS DMA, 16B per lane; lds dst is wave-uniform base + lane*16
static __device__ __forceinline__ void gload_lds16(const void* g, void* s) {
  __builtin_amdgcn_global_load_lds(
      (const __attribute__((address_space(1))) unsigned int*)g,
      (__attribute__((address_space(3))) unsigned int*)s, 16, 0, 0);
}

// Build wcat2 (A-fragment-packed [w_theta; w_phi; w_g]) and wo2 (fragment-packed).
__global__ __launch_bounds__(256) void k_wcvt(const float* __restrict__ w_theta,
                                              const float* __restrict__ w_phi,
                                              const float* __restrict__ w_g,
                                              const float* __restrict__ w_o,
                                              unsigned short* __restrict__ wcat2,
                                              unsigned short* __restrict__ wo2) {
  const int i = blockIdx.x * 256 + threadIdx.x;
  if (i < 49152) {
    const int row = i >> 8, c = i & 255;
    const float v = (row < 32) ? w_theta[i]
                  : (row < 64) ? w_phi[i - 8192]
                               : w_g[i - 16384];
    const int dst = ((row >> 4) * 8 + (c >> 5)) * 512 +
                    (((c >> 3) & 3) * 16 + (row & 15)) * 8 + (c & 7);
    wcat2[dst] = f2bf(v);
  } else {
    const int w = i - 49152;
    const int c_out = w >> 7, k = w & 127;
    const int dst = (((c_out >> 4) * 16) + ((k >> 5) * 4) + ((k >> 3) & 3)) * 128 +
                    ((c_out & 15) << 3) + (k & 7);
    wo2[dst] = f2bf(w_o[w]);
  }
}

// MFMA projection v4 (r23): r18 structure + T14 async-STAGE split.
// g2 V-fragments use the pi-permuted k-slot order so attn's P stays in registers.
__global__ __launch_bounds__(512) void k_proj(const float* __restrict__ x,
                                              const unsigned short* __restrict__ wcat2,
                                              unsigned short* __restrict__ theta,
                                              unsigned short* __restrict__ phi2,
                                              unsigned short* __restrict__ g2) {
  __shared__ unsigned short lds[192 * 136];  // union: xl2[2][32][132] | ol[192][136]
  unsigned short (*xl)[32][132] = reinterpret_cast<unsigned short(*)[32][132]>(lds);
  unsigned short (*ol)[136] = reinterpret_cast<unsigned short(*)[136]>(lds);
  const int b = blockIdx.y;
  const int t = blockIdx.x;
  const int tid = threadIdx.x;
  const int wv = tid >> 6;
  const int l = tid & 63;
  const int grp = l >> 4, col = l & 15;
  const float* xb = x + (size_t)b * CIN * NN;
  const int cl0 = tid >> 5, nq0 = tid & 31;
  const int cl1 = (tid + 512) >> 5, nq1 = tid & 31;
  float4 ra0, ra1;  // in-flight loads for the next chunk
  auto LOADX = [&](int kc) {
    ra0 = *reinterpret_cast<const float4*>(xb + (size_t)(kc * 32 + cl0) * NN + t * 128 + nq0 * 4);
    ra1 = *reinterpret_cast<const float4*>(xb + (size_t)(kc * 32 + cl1) * NN + t * 128 + nq1 * 4);
  };
  auto WRITEX = [&](int buf) {
    *reinterpret_cast<uint2*>(&xl[buf][cl0][nq0 * 4]) =
        make_uint2(pk2(ra0.x, ra0.y), pk2(ra0.z, ra0.w));
    *reinterpret_cast<uint2*>(&xl[buf][cl1][nq1 * 4]) =
        make_uint2(pk2(ra1.x, ra1.y), pk2(ra1.z, ra1.w));
  };
  f32x4 acc[12];
#pragma unroll
  for (int r = 0; r < 12; ++r) acc[r] = f32x4{0.f, 0.f, 0.f, 0.f};
  LOADX(0);
  WRITEX(0);
  LOADX(1);
#pragma unroll 1
  for (int kc = 0; kc < 8; ++kc) {
    __syncthreads();
    if (kc < 7) {
      WRITEX((kc + 1) & 1);
      if (kc < 6) LOADX(kc + 2);
    }
    const int cur = kc & 1;
    s16x8 bfrag;
#pragma unroll
    for (int j = 0; j < 8; ++j)
      bfrag[j] = (short)xl[cur][grp * 8 + j][wv * 16 + col];
#pragma unroll
    for (int r = 0; r < 12; ++r) {
      const s16x8 af = *reinterpret_cast<const s16x8*>(
          wcat2 + (size_t)(r * 8 + kc) * 512 + l * 8);
      acc[r] = __builtin_amdgcn_mfma_f32_16x16x32_bf16(af, bfrag, acc[r], 0, 0, 0);
    }
  }
  __syncthreads();
#pragma unroll
  for (int r = 0; r < 12; ++r)
#pragma unroll
    for (int q = 0; q < 4; ++q)
      ol[r * 16 + grp * 4 + q][wv * 16 + col] = f2bf(acc[r][q]);
  __syncthreads();
  unsigned short* thb = theta + (size_t)b * NN * CA;
  for (int i = tid; i < 128 * 16; i += 512) {
    const int n = i >> 4, cp = (i & 15) << 1;
    const unsigned int v = (unsigned)ol[cp][n] | ((unsigned)ol[cp + 1][n] << 16);
    *reinterpret_cast<unsigned int*>(thb + (size_t)(t * 128 + n) * CA + cp) = v;
  }
  unsigned short* phb2 = phi2 + (size_t)b * MM * CA;
  for (int i = tid; i < 32 * 32; i += 512) {
    const int ca = i & 31, mx = i >> 5;
    const float v = fmaxf(
        fmaxf(bf2f(ol[32 + ca][2 * mx]), bf2f(ol[32 + ca][2 * mx + 1])),
        fmaxf(bf2f(ol[32 + ca][64 + 2 * mx]), bf2f(ol[32 + ca][64 + 2 * mx + 1])));
    const int m = t * 32 + mx;
    phb2[(m >> 4) * 512 + (ca >> 3) * 128 + (m & 15) * 8 + (ca & 7)] = f2bf(v);
  }
  unsigned short* gb2 = g2 + (size_t)b * CH * MM;
  for (int i = tid; i < 128 * 32; i += 512) {
    const int mx = i & 31, c = i >> 5;
    const float v = fmaxf(
        fmaxf(bf2f(ol[64 + c][2 * mx]), bf2f(ol[64 + c][2 * mx + 1])),
        fmaxf(bf2f(ol[64 + c][64 + 2 * mx]), bf2f(ol[64 + c][64 + 2 * mx + 1])));
    const int pg = (mx & 15) >> 2;                       // pi: lane group
    const int pj = (mx & 3) | ((mx >> 4) << 2);          // pi: k-slot
    gb2[(size_t)(t * 8 + (c >> 4)) * 512 + pg * 128 + (c & 15) * 8 + pj] = f2bf(v);
  }
}

// Flash attention v15 (r30 champion): 128-key tiles (8 iterations), 8 waves x
// single-Q, shared dbuf DMA (40 x 1KB = 5/wave), register-P (pi), first-tile
// max, deferred denominator, truncating pack.
__global__ __launch_bounds__(512, 2) void k_attn_out(
    const unsigned short* __restrict__ theta, const unsigned short* __restrict__ phi2,
    const unsigned short* __restrict__ g2, const unsigned short* __restrict__ wo2,
    const float* __restrict__ x, const float* __restrict__ gammap,
    float* __restrict__ out) {
  __shared__ __align__(16) unsigned short kv[2][20480];  // [buf][K 4096 | V 16384]
  const int b = blockIdx.y;
  const int tid = threadIdx.x;
  const int wv = tid >> 6;  // 0..7
  const int l = tid & 63;
  const int grp = l >> 4, col = l & 15;
  const int n0 = blockIdx.x * 128 + wv * 16;
  const unsigned short* thb = theta + (size_t)b * NN * CA;
  const unsigned short* ph2b = phi2 + (size_t)b * MM * CA;
  const unsigned short* gb2 = g2 + (size_t)b * CH * MM;
  const s16x8 qf = *reinterpret_cast<const s16x8*>(thb + (size_t)(n0 + col) * CA + grp * 8);

  // 40 x 1KB DMA split over 8 waves (5 each): K 8KB + V 32KB per 128-key tile
  auto STAGE = [&](int buf, int tile) {
    const int mc = tile * 128;
    const unsigned short* ksrc = ph2b + (mc >> 4) * 512;
    const unsigned short* vsrc = gb2 + (size_t)(mc >> 5) * 4096;
#pragma unroll
    for (int q = 0; q < 5; ++q) {
      const int i = wv + q * 8;
      const unsigned short* src = (i < 8) ? (ksrc + i * 512) : (vsrc + (size_t)(i - 8) * 512);
      gload_lds16(src + (size_t)l * 8, &kv[buf][i * 512]);
    }
  };

  f32x4 oa[8];
#pragma unroll
  for (int t = 0; t < 8; ++t) oa[t] = f32x4{0.f, 0.f, 0.f, 0.f};
  float m0 = 0.f, ls = 0.f;  // m0 anchored at tile 0; ls: per-lane partial denom
  const f32x4 z4 = {0.f, 0.f, 0.f, 0.f};

  STAGE(0, 0);
  __syncthreads();
#pragma unroll 1
  for (int it = 0; it < 8; ++it) {
    const int cur = it & 1;
    if (it < 7) STAGE(cur ^ 1, it + 1);  // fire-and-forget DMA for next tile
    const unsigned short* kb = &kv[cur][0];
    const unsigned short* vb = &kv[cur][4096];
    const int fo = grp * 128 + col * 8;
    f32x4 s[8];
#pragma unroll
    for (int j = 0; j < 8; ++j) {
      const s16x8 kf = *reinterpret_cast<const s16x8*>(kb + j * 512 + fo);
      s[j] = __builtin_amdgcn_mfma_f32_16x16x32_bf16(kf, qf, z4, 0, 0, 0);
    }
    if (it == 0) {  // one exact cross-lane max; anchor for the whole row
      float cm = -INFINITY;
#pragma unroll
      for (int j = 0; j < 8; ++j)
#pragma unroll
        for (int r = 0; r < 4; ++r) cm = fmaxf(cm, s[j][r]);
      cm = fmaxf(cm, __shfl_xor(cm, 16));
      cm = fmaxf(cm, __shfl_xor(cm, 32));
      m0 = cm;
    }
    float p[8][4];
    float cs = 0.f;
#pragma unroll
    for (int j = 0; j < 8; ++j) {
#pragma unroll
      for (int r = 0; r < 4; ++r) {
        p[j][r] = __expf(s[j][r] - m0);
        cs += p[j][r];
      }
    }
    ls += cs;  // deferred: no cross-lane reduce in the loop
    s16x8 pf[4];
#pragma unroll
    for (int c2 = 0; c2 < 4; ++c2) {  // 4 P fragments, each covering 32 keys
      const uint4 u = make_uint4(
          pk2t(p[2 * c2][0], p[2 * c2][1]), pk2t(p[2 * c2][2], p[2 * c2][3]),
          pk2t(p[2 * c2 + 1][0], p[2 * c2 + 1][1]),
          pk2t(p[2 * c2 + 1][2], p[2 * c2 + 1][3]));
      pf[c2] = __builtin_bit_cast(s16x8, u);
    }
#pragma unroll
    for (int c2 = 0; c2 < 4; ++c2) {
#pragma unroll
      for (int t = 0; t < 8; ++t) {
        const s16x8 vf = *reinterpret_cast<const s16x8*>(vb + c2 * 4096 + t * 512 + fo);
        oa[t] = __builtin_amdgcn_mfma_f32_16x16x32_bf16(vf, pf[c2], oa[t], 0, 0, 0);
      }
    }
    __syncthreads();  // drains DMA (vmcnt) + syncs buffer swap
  }
  // final denominator reduce (deferred from loop)
  ls += __shfl_xor(ls, 16);
  ls += __shfl_xor(ls, 32);
  // ---- epilogue: normalize own O, stage in LDS (reuse kv), project ----
  unsigned short* obw = &kv[0][0] + (size_t)wv * (16 * 136);
  const float ri = 1.f / ls;
#pragma unroll
  for (int t = 0; t < 8; ++t) {
    *reinterpret_cast<uint2*>(obw + col * 136 + t * 16 + grp * 4) =
        make_uint2(pk2t(oa[t][0] * ri, oa[t][1] * ri),
                   pk2t(oa[t][2] * ri, oa[t][3] * ri));
  }
  s16x8 of[4];
#pragma unroll
  for (int ks = 0; ks < 4; ++ks)
    of[ks] = *reinterpret_cast<const s16x8*>(obw + col * 136 + ks * 32 + grp * 8);
  const float gamma = gammap[0];
  const float* xb2 = x + (size_t)b * CIN * NN;
  float* outb = out + (size_t)b * CIN * NN;
#pragma unroll 1
  for (int t2 = 0; t2 < 16; ++t2) {
    f32x4 a2 = {0.f, 0.f, 0.f, 0.f};
#pragma unroll
    for (int ks = 0; ks < 4; ++ks) {
      const s16x8 wf = *reinterpret_cast<const s16x8*>(
          wo2 + (size_t)(t2 * 16 + ks * 4 + grp) * 128 + col * 8);
      a2 = __builtin_amdgcn_mfma_f32_16x16x32_bf16(wf, of[ks], a2, 0, 0, 0);
    }
#pragma unroll
    for (int r = 0; r < 4; ++r) {
      const size_t idx = (size_t)(t2 * 16 + grp * 4 + r) * NN + n0 + col;
      outb[idx] = fmaf(gamma, a2[r], xb2[idx]);
    }
  }
}

extern "C" void kernel_launch(void* const* d_in, const int* in_sizes, int n_in,
                              void* d_out, int out_size, void* d_ws, size_t ws_size,
                              hipStream_t stream) {
  const float* x = (const float*)d_in[0];
  const float* w_theta = (const float*)d_in[1];
  const float* w_phi = (const float*)d_in[2];
  const float* w_g = (const float*)d_in[3];
  const float* w_o = (const float*)d_in[4];
  const float* gamma = (const float*)d_in[5];
  float* out = (float*)d_out;
  char* ws = (char*)d_ws;
  unsigned short* theta = (unsigned short*)(ws + 0);
  unsigned short* phi2 = (unsigned short*)(ws + 4194304);
  unsigned short* g2 = (unsigned short*)(ws + 5242880);
  unsigned short* wo2 = (unsigned short*)(ws + 9437184);
  unsigned short* wcat2 = (unsigned short*)(ws + 9502720);

  k_wcvt<<<dim3(320), 256, 0, stream>>>(w_theta, w_phi, w_g, w_o, wcat2, wo2);
  k_proj<<<dim3(NN / 128, NB), 512, 0, stream>>>(x, wcat2, theta, phi2, g2);
  k_attn_out<<<dim3(NN / 128, NB), 512, 0, stream>>>(theta, phi2, g2, wo2, x, gamma, out);
}